// Round 3
// baseline (737.149 us; speedup 1.0000x reference)
//
#include <hip/hip_runtime.h>
#include <hip/hip_bf16.h>

// Problem constants (match reference)
#define N_NODES  100000
#define N_EDGES  1600000
#define N_GRAPHS 2048
#define DIM      128   // IN_DIM == HIDDEN == 128

// ===========================================================================
// CSR construction: count -> 3-phase exclusive scan -> cursor fill
// ===========================================================================
__global__ __launch_bounds__(256)
void cnt_kernel(const int* __restrict__ dst, int* __restrict__ cnt, int E)
{
    int e0 = (blockIdx.x * blockDim.x + threadIdx.x) * 4;
    if (e0 + 3 < E) {
        int4 d = *(const int4*)&dst[e0];
        atomicAdd(&cnt[d.x], 1);
        atomicAdd(&cnt[d.y], 1);
        atomicAdd(&cnt[d.z], 1);
        atomicAdd(&cnt[d.w], 1);
    } else {
        for (int e = e0; e < E; ++e) atomicAdd(&cnt[dst[e]], 1);
    }
}

#define SCAN_T     256
#define SCAN_E     4
#define SCAN_CHUNK 1024   // SCAN_T * SCAN_E
#define SCAN_NBLK  ((N_NODES + SCAN_CHUNK - 1) / SCAN_CHUNK)   // 98

// Phase 1: per-block local exclusive scan of cnt -> rp, block totals -> bsum
__global__ __launch_bounds__(SCAN_T)
void scan1(const int* __restrict__ cnt, int* __restrict__ rp,
           int* __restrict__ bsum, int N)
{
    __shared__ int sh[SCAN_T];
    int b = blockIdx.x, t = threadIdx.x;
    int base = b * SCAN_CHUNK + t * SCAN_E;
    int v[SCAN_E];
    int s = 0;
#pragma unroll
    for (int i = 0; i < SCAN_E; ++i) {
        int idx = base + i;
        v[i] = (idx < N) ? cnt[idx] : 0;
        s += v[i];
    }
    sh[t] = s;
    __syncthreads();
    for (int off = 1; off < SCAN_T; off <<= 1) {
        int add = (t >= off) ? sh[t - off] : 0;
        __syncthreads();
        sh[t] += add;
        __syncthreads();
    }
    int excl = sh[t] - s;
    if (t == SCAN_T - 1) bsum[b] = sh[t];
    int run = excl;
#pragma unroll
    for (int i = 0; i < SCAN_E; ++i) {
        int idx = base + i;
        if (idx < N) rp[idx] = run;
        run += v[i];
    }
}

// Phase 2: single-block exclusive scan of block sums (SCAN_NBLK <= 128)
__global__ __launch_bounds__(128)
void scan2(int* __restrict__ bsum, int nb)
{
    __shared__ int sh[128];
    int t = threadIdx.x;
    int v = (t < nb) ? bsum[t] : 0;
    sh[t] = v;
    __syncthreads();
    for (int off = 1; off < 128; off <<= 1) {
        int add = (t >= off) ? sh[t - off] : 0;
        __syncthreads();
        sh[t] += add;
        __syncthreads();
    }
    if (t < nb) bsum[t] = sh[t] - v;   // exclusive
}

// Phase 3: add block offsets; emit row_ptr and cursor copies; rp[N] = E
__global__ __launch_bounds__(256)
void scan3(int* __restrict__ rp, int* __restrict__ cursor,
           const int* __restrict__ bsum, int N, int E)
{
    int i = blockIdx.x * blockDim.x + threadIdx.x;
    if (i < N) {
        int v = rp[i] + bsum[i / SCAN_CHUNK];
        rp[i] = v;
        cursor[i] = v;
    }
    if (i == N) rp[N] = E;
}

// Batched x4: issue 4 independent atomics (latency overlap), then 4 stores.
__global__ __launch_bounds__(256)
void csr_fill(const int* __restrict__ src, const int* __restrict__ dst,
              int* __restrict__ cursor, int* __restrict__ csr, int E)
{
    int e0 = (blockIdx.x * blockDim.x + threadIdx.x) * 4;
    if (e0 + 3 < E) {
        int4 d = *(const int4*)&dst[e0];
        int4 s = *(const int4*)&src[e0];
        int p0 = atomicAdd(&cursor[d.x], 1);
        int p1 = atomicAdd(&cursor[d.y], 1);
        int p2 = atomicAdd(&cursor[d.z], 1);
        int p3 = atomicAdd(&cursor[d.w], 1);
        csr[p0] = s.x;
        csr[p1] = s.y;
        csr[p2] = s.z;
        csr[p3] = s.w;
    } else {
        for (int e = e0; e < E; ++e) {
            int pos = atomicAdd(&cursor[dst[e]], 1);
            csr[pos] = src[e];
        }
    }
}

// In-place reinterpret: int count -> float rsqrt(count + 1)
__global__ __launch_bounds__(256)
void make_dinv(int* __restrict__ cnt, int N)
{
    int i = blockIdx.x * blockDim.x + threadIdx.x;
    if (i < N) {
        float d = (float)cnt[i] + 1.0f;
        ((float*)cnt)[i] = rsqrtf(d);
    }
}

// ===========================================================================
// CSR gather: Out[i] = V[i] + sum_{e in [rp[i],rp[i+1])} V[csr[e]]
// One node per 32-lane group, float4 per lane. Unrolled x4 so 4 row-loads
// are in flight per lane (latency-bound kernel).
// ===========================================================================
__global__ __launch_bounds__(256)
void csr_gather(const int* __restrict__ rp, const int* __restrict__ csr,
                const float* __restrict__ V, float* __restrict__ Out, int N)
{
    int node = blockIdx.x * 8 + (threadIdx.x >> 5);
    int lane = threadIdx.x & 31;
    if (node >= N) return;
    int beg = rp[node];
    int end = rp[node + 1];
    const float4* V4 = (const float4*)V;
    float4 acc = V4[(size_t)node * 32 + lane];   // self term
    int e = beg;
    for (; e + 4 <= end; e += 4) {
        int s0 = csr[e + 0];
        int s1 = csr[e + 1];
        int s2 = csr[e + 2];
        int s3 = csr[e + 3];
        float4 v0 = V4[(size_t)s0 * 32 + lane];
        float4 v1 = V4[(size_t)s1 * 32 + lane];
        float4 v2 = V4[(size_t)s2 * 32 + lane];
        float4 v3 = V4[(size_t)s3 * 32 + lane];
        acc.x += v0.x + v1.x + v2.x + v3.x;
        acc.y += v0.y + v1.y + v2.y + v3.y;
        acc.z += v0.z + v1.z + v2.z + v3.z;
        acc.w += v0.w + v1.w + v2.w + v3.w;
    }
    for (; e < end; ++e) {
        int s = csr[e];
        float4 v = V4[(size_t)s * 32 + lane];
        acc.x += v.x; acc.y += v.y; acc.z += v.z; acc.w += v.w;
    }
    ((float4*)Out)[(size_t)node * 32 + lane] = acc;
}

// ===========================================================================
// Register-tiled fp32 GEMM: Out[i][n] = f( sum_k A[i][k] * W[k][n] )
//   K = N = 128 fixed, M runtime. Block tile 128x128, thread tile 8x8,
//   256 threads. Epilogue: +bias (if non-null), *dinv[row] (if SCALE_DINV),
//   relu (if RELU).
// ===========================================================================
#define BM 128
#define BK 32

template<bool RELU, bool SCALE_DINV>
__global__ __launch_bounds__(256)
void gemm128(const float* __restrict__ A, const float* __restrict__ W,
             const float* __restrict__ bias, const float* __restrict__ dinv,
             float* __restrict__ Out, int M)
{
    __shared__ float At[BK][BM + 4];   // transposed A tile
    __shared__ float Bs[BK][DIM];

    const int tid = threadIdx.x;
    const int tx  = tid & 15;    // 16 col groups * 8 cols = 128
    const int ty  = tid >> 4;    // 16 row groups * 8 rows = 128
    const int row0 = blockIdx.x * BM;

    float acc[8][8];
#pragma unroll
    for (int i = 0; i < 8; ++i)
#pragma unroll
        for (int j = 0; j < 8; ++j) acc[i][j] = 0.f;

    for (int kt = 0; kt < DIM; kt += BK) {
        // stage A tile (transposed): 128 rows x 32 k = 1024 float4, 4/thread
#pragma unroll
        for (int l = 0; l < 4; ++l) {
            int f  = tid + l * 256;
            int r  = f >> 3;
            int kc = (f & 7) << 2;
            int gr = row0 + r;
            float4 v = make_float4(0.f, 0.f, 0.f, 0.f);
            if (gr < M) v = *(const float4*)&A[(size_t)gr * DIM + kt + kc];
            At[kc + 0][r] = v.x;
            At[kc + 1][r] = v.y;
            At[kc + 2][r] = v.z;
            At[kc + 3][r] = v.w;
        }
        // stage W tile: 32 rows x 128 cols = 1024 float4, 4/thread
#pragma unroll
        for (int l = 0; l < 4; ++l) {
            int f  = tid + l * 256;
            int r  = f >> 5;
            int c4 = (f & 31) << 2;
            *(float4*)&Bs[r][c4] = *(const float4*)&W[(size_t)(kt + r) * DIM + c4];
        }
        __syncthreads();

#pragma unroll
        for (int kk = 0; kk < BK; ++kk) {
            float a[8], b[8];
            *(float4*)&a[0] = *(const float4*)&At[kk][ty * 8 + 0];
            *(float4*)&a[4] = *(const float4*)&At[kk][ty * 8 + 4];
            *(float4*)&b[0] = *(const float4*)&Bs[kk][tx * 8 + 0];
            *(float4*)&b[4] = *(const float4*)&Bs[kk][tx * 8 + 4];
#pragma unroll
            for (int i = 0; i < 8; ++i)
#pragma unroll
                for (int j = 0; j < 8; ++j)
                    acc[i][j] = fmaf(a[i], b[j], acc[i][j]);
        }
        __syncthreads();
    }

    // epilogue
    const int c0 = tx * 8;
#pragma unroll
    for (int i = 0; i < 8; ++i) {
        int r = row0 + ty * 8 + i;
        if (r < M) {
            float v[8];
#pragma unroll
            for (int j = 0; j < 8; ++j) v[j] = acc[i][j];
            if (bias) {
#pragma unroll
                for (int j = 0; j < 8; ++j) v[j] += bias[c0 + j];
            }
            if (SCALE_DINV) {
                float di = dinv[r];
#pragma unroll
                for (int j = 0; j < 8; ++j) v[j] *= di;
            }
            if (RELU) {
#pragma unroll
                for (int j = 0; j < 8; ++j) v[j] = fmaxf(v[j], 0.f);
            }
            *(float4*)&Out[(size_t)r * DIM + c0 + 0] = *(const float4*)&v[0];
            *(float4*)&Out[(size_t)r * DIM + c0 + 4] = *(const float4*)&v[4];
        }
    }
}

// ===========================================================================
// Finalize GCN + global_add_pool (batch sorted -> run-length local sums)
// ===========================================================================
#define POOL_ROWS 64
__global__ __launch_bounds__(128)
void finalize_pool(const float* __restrict__ Acc, const float* __restrict__ dinv,
                   const float* __restrict__ bias, const int* __restrict__ batch,
                   float* __restrict__ g, int N)
{
    int row0 = blockIdx.x * POOL_ROWS;
    int j = threadIdx.x;
    float bj = bias[j];
    float local = 0.f;
    int prev = -1;
    int rend = row0 + POOL_ROWS;
    if (rend > N) rend = N;
    for (int r = row0; r < rend; ++r) {
        int b = batch[r];
        if (b != prev) {
            if (prev >= 0) atomicAdd(&g[(size_t)prev * DIM + j], local);
            local = 0.f;
            prev = b;
        }
        float v = fmaf(dinv[r], Acc[(size_t)r * DIM + j], bj);
        local += fmaxf(v, 0.f);
    }
    if (prev >= 0) atomicAdd(&g[(size_t)prev * DIM + j], local);
}

// ===========================================================================
// Head: out[gid] = relu(g[gid] @ lin1_w + b1) @ lin2_w + b2
// ===========================================================================
__global__ __launch_bounds__(128)
void head_kernel(const float* __restrict__ g, const float* __restrict__ w1,
                 const float* __restrict__ b1, const float* __restrict__ w2,
                 const float* __restrict__ b2, float* __restrict__ out)
{
    __shared__ float gs[DIM];
    __shared__ float red[6];
    int gid = blockIdx.x;
    int t = threadIdx.x;

    gs[t] = g[(size_t)gid * DIM + t];
    __syncthreads();

    float acc = b1[t];
#pragma unroll
    for (int k = 0; k < DIM; ++k) acc = fmaf(gs[k], w1[k * DIM + t], acc);
    float h = fmaxf(acc, 0.f);

    float c0 = h * w2[t * 3 + 0];
    float c1 = h * w2[t * 3 + 1];
    float c2 = h * w2[t * 3 + 2];
#pragma unroll
    for (int off = 32; off >= 1; off >>= 1) {
        c0 += __shfl_down(c0, off);
        c1 += __shfl_down(c1, off);
        c2 += __shfl_down(c2, off);
    }
    int wave = t >> 6;
    if ((t & 63) == 0) {
        red[wave * 3 + 0] = c0;
        red[wave * 3 + 1] = c1;
        red[wave * 3 + 2] = c2;
    }
    __syncthreads();
    if (t == 0) {
        out[(size_t)gid * 3 + 0] = red[0] + red[3] + b2[0];
        out[(size_t)gid * 3 + 1] = red[1] + red[4] + b2[1];
        out[(size_t)gid * 3 + 2] = red[2] + red[5] + b2[2];
    }
}

// ===========================================================================
extern "C" void kernel_launch(void* const* d_in, const int* in_sizes, int n_in,
                              void* d_out, int out_size, void* d_ws, size_t ws_size,
                              hipStream_t stream)
{
    const float* x       = (const float*)d_in[0];
    const int*   eidx    = (const int*)d_in[1];
    const int*   batch   = (const int*)d_in[2];
    const float* gin_w1  = (const float*)d_in[3];
    const float* gin_b1  = (const float*)d_in[4];
    const float* gin_w2  = (const float*)d_in[5];
    const float* gin_b2  = (const float*)d_in[6];
    const float* gcn_w   = (const float*)d_in[7];
    const float* gcn_b   = (const float*)d_in[8];
    const float* lin1_w  = (const float*)d_in[9];
    const float* lin1_b  = (const float*)d_in[10];
    const float* lin2_w  = (const float*)d_in[11];
    const float* lin2_b  = (const float*)d_in[12];

    const int* src = eidx;
    const int* dst = eidx + N_EDGES;

    // workspace carve (256B aligned)
    const size_t NB = (size_t)N_NODES * DIM * sizeof(float);   // 51.2 MB
    char* base = (char*)d_ws;
    size_t off = 0;
    auto carve = [&](size_t bytes) {
        char* p = base + off;
        off = (off + bytes + 255) & ~(size_t)255;
        return p;
    };
    float* bufA   = (float*)carve(NB);
    float* bufB   = (float*)carve(NB);
    int*   cnt    = (int*)  carve(N_NODES * sizeof(int));      // cnt -> dinv
    int*   rp     = (int*)  carve((N_NODES + 1) * sizeof(int));
    int*   cursor = (int*)  carve(N_NODES * sizeof(int));
    int*   csr    = (int*)  carve((size_t)N_EDGES * sizeof(int));
    int*   bsum   = (int*)  carve(SCAN_NBLK * sizeof(int));
    float* g      = (float*)carve((size_t)N_GRAPHS * DIM * sizeof(float));
    float* dinv   = (float*)cnt;   // in-place conversion after CSR build

    hipMemsetAsync(cnt, 0, N_NODES * sizeof(int), stream);
    hipMemsetAsync(g, 0, (size_t)N_GRAPHS * DIM * sizeof(float), stream);

    const int egrid4 = (N_EDGES / 4 + 255) / 256;
    const int ngrid  = (N_NODES + 7) / 8;
    const int ggrid  = (N_NODES + BM - 1) / BM;

    // ---- CSR build ----
    cnt_kernel<<<egrid4, 256, 0, stream>>>(dst, cnt, N_EDGES);
    scan1<<<SCAN_NBLK, SCAN_T, 0, stream>>>(cnt, rp, bsum, N_NODES);
    scan2<<<1, 128, 0, stream>>>(bsum, SCAN_NBLK);
    scan3<<<(N_NODES + 256) / 256, 256, 0, stream>>>(rp, cursor, bsum, N_NODES, N_EDGES);
    csr_fill<<<egrid4, 256, 0, stream>>>(src, dst, cursor, csr, N_EDGES);
    make_dinv<<<(N_NODES + 255) / 256, 256, 0, stream>>>(cnt, N_NODES);

    // ---- GIN: bufA = x + segment_sum(x[src], dst) ----
    csr_gather<<<ngrid, 256, 0, stream>>>(rp, csr, x, bufA, N_NODES);

    // ---- GIN MLP ----
    gemm128<true,  false><<<ggrid, 256, 0, stream>>>(bufA, gin_w1, gin_b1, nullptr, bufB, N_NODES);
    gemm128<true,  false><<<ggrid, 256, 0, stream>>>(bufB, gin_w2, gin_b2, nullptr, bufA, N_NODES);

    // ---- GCN: u = dinv * (h @ gcn_w) -> bufB ----
    gemm128<false, true><<<ggrid, 256, 0, stream>>>(bufA, gcn_w, nullptr, dinv, bufB, N_NODES);

    // ---- GCN message pass: bufA[i] = u[i] + sum u[csr] ----
    csr_gather<<<ngrid, 256, 0, stream>>>(rp, csr, bufB, bufA, N_NODES);

    // ---- finalize + pool ----
    finalize_pool<<<(N_NODES + POOL_ROWS - 1) / POOL_ROWS, 128, 0, stream>>>(
        bufA, dinv, gcn_b, batch, g, N_NODES);

    // ---- head ----
    head_kernel<<<N_GRAPHS, 128, 0, stream>>>(
        g, lin1_w, lin1_b, lin2_w, lin2_b, (float*)d_out);
}

// Round 4
// 685.584 us; speedup vs baseline: 1.0752x; 1.0752x over previous
//
#include <hip/hip_runtime.h>
#include <hip/hip_bf16.h>

// Problem constants (match reference)
#define N_NODES  100000
#define N_EDGES  1600000
#define N_GRAPHS 2048
#define DIM      128   // IN_DIM == HIDDEN == 128

// ===========================================================================
// CSR construction: count -> 3-phase exclusive scan -> XCD-partitioned fill
// ===========================================================================
__global__ __launch_bounds__(256)
void cnt_kernel(const int* __restrict__ dst, int* __restrict__ cnt, int E)
{
    int e0 = (blockIdx.x * blockDim.x + threadIdx.x) * 4;
    if (e0 + 3 < E) {
        int4 d = *(const int4*)&dst[e0];
        atomicAdd(&cnt[d.x], 1);
        atomicAdd(&cnt[d.y], 1);
        atomicAdd(&cnt[d.z], 1);
        atomicAdd(&cnt[d.w], 1);
    } else {
        for (int e = e0; e < E; ++e) atomicAdd(&cnt[dst[e]], 1);
    }
}

#define SCAN_T     256
#define SCAN_E     4
#define SCAN_CHUNK 1024   // SCAN_T * SCAN_E
#define SCAN_NBLK  ((N_NODES + SCAN_CHUNK - 1) / SCAN_CHUNK)   // 98

// Phase 1: per-block local exclusive scan of cnt -> rp, block totals -> bsum
__global__ __launch_bounds__(SCAN_T)
void scan1(const int* __restrict__ cnt, int* __restrict__ rp,
           int* __restrict__ bsum, int N)
{
    __shared__ int sh[SCAN_T];
    int b = blockIdx.x, t = threadIdx.x;
    int base = b * SCAN_CHUNK + t * SCAN_E;
    int v[SCAN_E];
    int s = 0;
#pragma unroll
    for (int i = 0; i < SCAN_E; ++i) {
        int idx = base + i;
        v[i] = (idx < N) ? cnt[idx] : 0;
        s += v[i];
    }
    sh[t] = s;
    __syncthreads();
    for (int off = 1; off < SCAN_T; off <<= 1) {
        int add = (t >= off) ? sh[t - off] : 0;
        __syncthreads();
        sh[t] += add;
        __syncthreads();
    }
    int excl = sh[t] - s;
    if (t == SCAN_T - 1) bsum[b] = sh[t];
    int run = excl;
#pragma unroll
    for (int i = 0; i < SCAN_E; ++i) {
        int idx = base + i;
        if (idx < N) rp[idx] = run;
        run += v[i];
    }
}

// Phase 2: single-block exclusive scan of block sums (SCAN_NBLK <= 128)
__global__ __launch_bounds__(128)
void scan2(int* __restrict__ bsum, int nb)
{
    __shared__ int sh[128];
    int t = threadIdx.x;
    int v = (t < nb) ? bsum[t] : 0;
    sh[t] = v;
    __syncthreads();
    for (int off = 1; off < 128; off <<= 1) {
        int add = (t >= off) ? sh[t - off] : 0;
        __syncthreads();
        sh[t] += add;
        __syncthreads();
    }
    if (t < nb) bsum[t] = sh[t] - v;   // exclusive
}

// Phase 3: add block offsets; emit row_ptr and cursor copies; rp[N] = E
__global__ __launch_bounds__(256)
void scan3(int* __restrict__ rp, int* __restrict__ cursor,
           const int* __restrict__ bsum, int N, int E)
{
    int i = blockIdx.x * blockDim.x + threadIdx.x;
    if (i < N) {
        int v = rp[i] + bsum[i / SCAN_CHUNK];
        rp[i] = v;
        cursor[i] = v;
    }
    if (i == N) rp[N] = E;
}

// XCD-partitioned fill: range r = blockIdx & 7 owns dst in [r*12500,(r+1)*12500).
// All range-r blocks land on one XCD (round-robin dispatch heuristic), so all
// 16 stores filling any csr cacheline coalesce in that XCD's L2 (800 KB
// window << 4 MB L2) instead of 64B-per-store HBM write amplification.
#define FILL_RANGES 8
#define FILL_RSIZE  (N_NODES / FILL_RANGES)   // 12500 exact
__global__ __launch_bounds__(256)
void csr_fill(const int* __restrict__ src, const int* __restrict__ dst,
              int* __restrict__ cursor, int* __restrict__ csr, int E)
{
    const int r = blockIdx.x & (FILL_RANGES - 1);
    const int s = blockIdx.x >> 3;
    const int nslice = gridDim.x >> 3;
    const unsigned lo = (unsigned)(r * FILL_RSIZE);
    const int stride = nslice * 256 * 4;

    for (int e0 = (s * 256 + threadIdx.x) * 4; e0 < E; e0 += stride) {
        int4 d  = *(const int4*)&dst[e0];
        int4 sv = *(const int4*)&src[e0];
        if ((unsigned)(d.x - lo) < (unsigned)FILL_RSIZE) {
            int p = atomicAdd(&cursor[d.x], 1); csr[p] = sv.x;
        }
        if ((unsigned)(d.y - lo) < (unsigned)FILL_RSIZE) {
            int p = atomicAdd(&cursor[d.y], 1); csr[p] = sv.y;
        }
        if ((unsigned)(d.z - lo) < (unsigned)FILL_RSIZE) {
            int p = atomicAdd(&cursor[d.z], 1); csr[p] = sv.z;
        }
        if ((unsigned)(d.w - lo) < (unsigned)FILL_RSIZE) {
            int p = atomicAdd(&cursor[d.w], 1); csr[p] = sv.w;
        }
    }
}

// In-place reinterpret: int count -> float rsqrt(count + 1)
__global__ __launch_bounds__(256)
void make_dinv(int* __restrict__ cnt, int N)
{
    int i = blockIdx.x * blockDim.x + threadIdx.x;
    if (i < N) {
        float d = (float)cnt[i] + 1.0f;
        ((float*)cnt)[i] = rsqrtf(d);
    }
}

// ===========================================================================
// CSR gather: Out[i] = V[i] + sum_{e in [rp[i],rp[i+1])} V[csr[e]]
// One node per 32-lane group, float4 per lane, x4 unroll for MLP-in-flight.
// ===========================================================================
__global__ __launch_bounds__(256)
void csr_gather(const int* __restrict__ rp, const int* __restrict__ csr,
                const float* __restrict__ V, float* __restrict__ Out, int N)
{
    int node = blockIdx.x * 8 + (threadIdx.x >> 5);
    int lane = threadIdx.x & 31;
    if (node >= N) return;
    int beg = rp[node];
    int end = rp[node + 1];
    const float4* V4 = (const float4*)V;
    float4 acc = V4[(size_t)node * 32 + lane];   // self term
    int e = beg;
    for (; e + 4 <= end; e += 4) {
        int s0 = csr[e + 0];
        int s1 = csr[e + 1];
        int s2 = csr[e + 2];
        int s3 = csr[e + 3];
        float4 v0 = V4[(size_t)s0 * 32 + lane];
        float4 v1 = V4[(size_t)s1 * 32 + lane];
        float4 v2 = V4[(size_t)s2 * 32 + lane];
        float4 v3 = V4[(size_t)s3 * 32 + lane];
        acc.x += v0.x + v1.x + v2.x + v3.x;
        acc.y += v0.y + v1.y + v2.y + v3.y;
        acc.z += v0.z + v1.z + v2.z + v3.z;
        acc.w += v0.w + v1.w + v2.w + v3.w;
    }
    for (; e < end; ++e) {
        int s = csr[e];
        float4 v = V4[(size_t)s * 32 + lane];
        acc.x += v.x; acc.y += v.y; acc.z += v.z; acc.w += v.w;
    }
    ((float4*)Out)[(size_t)node * 32 + lane] = acc;
}

// ===========================================================================
// Register-tiled fp32 GEMM: Out[i][n] = f( sum_k A[i][k] * W[k][n] )
//   K = N = 128 fixed. Block tile 128x128, thread tile 8x8, 256 threads.
// ===========================================================================
#define BM 128
#define BK 32

template<bool RELU, bool SCALE_DINV>
__global__ __launch_bounds__(256)
void gemm128(const float* __restrict__ A, const float* __restrict__ W,
             const float* __restrict__ bias, const float* __restrict__ dinv,
             float* __restrict__ Out, int M)
{
    __shared__ float At[BK][BM + 4];
    __shared__ float Bs[BK][DIM];

    const int tid = threadIdx.x;
    const int tx  = tid & 15;
    const int ty  = tid >> 4;
    const int row0 = blockIdx.x * BM;

    float acc[8][8];
#pragma unroll
    for (int i = 0; i < 8; ++i)
#pragma unroll
        for (int j = 0; j < 8; ++j) acc[i][j] = 0.f;

    for (int kt = 0; kt < DIM; kt += BK) {
#pragma unroll
        for (int l = 0; l < 4; ++l) {
            int f  = tid + l * 256;
            int r  = f >> 3;
            int kc = (f & 7) << 2;
            int gr = row0 + r;
            float4 v = make_float4(0.f, 0.f, 0.f, 0.f);
            if (gr < M) v = *(const float4*)&A[(size_t)gr * DIM + kt + kc];
            At[kc + 0][r] = v.x;
            At[kc + 1][r] = v.y;
            At[kc + 2][r] = v.z;
            At[kc + 3][r] = v.w;
        }
#pragma unroll
        for (int l = 0; l < 4; ++l) {
            int f  = tid + l * 256;
            int r  = f >> 5;
            int c4 = (f & 31) << 2;
            *(float4*)&Bs[r][c4] = *(const float4*)&W[(size_t)(kt + r) * DIM + c4];
        }
        __syncthreads();

#pragma unroll
        for (int kk = 0; kk < BK; ++kk) {
            float a[8], b[8];
            *(float4*)&a[0] = *(const float4*)&At[kk][ty * 8 + 0];
            *(float4*)&a[4] = *(const float4*)&At[kk][ty * 8 + 4];
            *(float4*)&b[0] = *(const float4*)&Bs[kk][tx * 8 + 0];
            *(float4*)&b[4] = *(const float4*)&Bs[kk][tx * 8 + 4];
#pragma unroll
            for (int i = 0; i < 8; ++i)
#pragma unroll
                for (int j = 0; j < 8; ++j)
                    acc[i][j] = fmaf(a[i], b[j], acc[i][j]);
        }
        __syncthreads();
    }

    const int c0 = tx * 8;
#pragma unroll
    for (int i = 0; i < 8; ++i) {
        int r = row0 + ty * 8 + i;
        if (r < M) {
            float v[8];
#pragma unroll
            for (int j = 0; j < 8; ++j) v[j] = acc[i][j];
            if (bias) {
#pragma unroll
                for (int j = 0; j < 8; ++j) v[j] += bias[c0 + j];
            }
            if (SCALE_DINV) {
                float di = dinv[r];
#pragma unroll
                for (int j = 0; j < 8; ++j) v[j] *= di;
            }
            if (RELU) {
#pragma unroll
                for (int j = 0; j < 8; ++j) v[j] = fmaxf(v[j], 0.f);
            }
            *(float4*)&Out[(size_t)r * DIM + c0 + 0] = *(const float4*)&v[0];
            *(float4*)&Out[(size_t)r * DIM + c0 + 4] = *(const float4*)&v[4];
        }
    }
}

// ===========================================================================
// Finalize GCN + global_add_pool (batch sorted -> run-length local sums)
// ===========================================================================
#define POOL_ROWS 64
__global__ __launch_bounds__(128)
void finalize_pool(const float* __restrict__ Acc, const float* __restrict__ dinv,
                   const float* __restrict__ bias, const int* __restrict__ batch,
                   float* __restrict__ g, int N)
{
    int row0 = blockIdx.x * POOL_ROWS;
    int j = threadIdx.x;
    float bj = bias[j];
    float local = 0.f;
    int prev = -1;
    int rend = row0 + POOL_ROWS;
    if (rend > N) rend = N;
    for (int r = row0; r < rend; ++r) {
        int b = batch[r];
        if (b != prev) {
            if (prev >= 0) atomicAdd(&g[(size_t)prev * DIM + j], local);
            local = 0.f;
            prev = b;
        }
        float v = fmaf(dinv[r], Acc[(size_t)r * DIM + j], bj);
        local += fmaxf(v, 0.f);
    }
    if (prev >= 0) atomicAdd(&g[(size_t)prev * DIM + j], local);
}

// ===========================================================================
// Head: out[gid] = relu(g[gid] @ lin1_w + b1) @ lin2_w + b2
// ===========================================================================
__global__ __launch_bounds__(128)
void head_kernel(const float* __restrict__ g, const float* __restrict__ w1,
                 const float* __restrict__ b1, const float* __restrict__ w2,
                 const float* __restrict__ b2, float* __restrict__ out)
{
    __shared__ float gs[DIM];
    __shared__ float red[6];
    int gid = blockIdx.x;
    int t = threadIdx.x;

    gs[t] = g[(size_t)gid * DIM + t];
    __syncthreads();

    float acc = b1[t];
#pragma unroll
    for (int k = 0; k < DIM; ++k) acc = fmaf(gs[k], w1[k * DIM + t], acc);
    float h = fmaxf(acc, 0.f);

    float c0 = h * w2[t * 3 + 0];
    float c1 = h * w2[t * 3 + 1];
    float c2 = h * w2[t * 3 + 2];
#pragma unroll
    for (int off = 32; off >= 1; off >>= 1) {
        c0 += __shfl_down(c0, off);
        c1 += __shfl_down(c1, off);
        c2 += __shfl_down(c2, off);
    }
    int wave = t >> 6;
    if ((t & 63) == 0) {
        red[wave * 3 + 0] = c0;
        red[wave * 3 + 1] = c1;
        red[wave * 3 + 2] = c2;
    }
    __syncthreads();
    if (t == 0) {
        out[(size_t)gid * 3 + 0] = red[0] + red[3] + b2[0];
        out[(size_t)gid * 3 + 1] = red[1] + red[4] + b2[1];
        out[(size_t)gid * 3 + 2] = red[2] + red[5] + b2[2];
    }
}

// ===========================================================================
extern "C" void kernel_launch(void* const* d_in, const int* in_sizes, int n_in,
                              void* d_out, int out_size, void* d_ws, size_t ws_size,
                              hipStream_t stream)
{
    const float* x       = (const float*)d_in[0];
    const int*   eidx    = (const int*)d_in[1];
    const int*   batch   = (const int*)d_in[2];
    const float* gin_w1  = (const float*)d_in[3];
    const float* gin_b1  = (const float*)d_in[4];
    const float* gin_w2  = (const float*)d_in[5];
    const float* gin_b2  = (const float*)d_in[6];
    const float* gcn_w   = (const float*)d_in[7];
    const float* gcn_b   = (const float*)d_in[8];
    const float* lin1_w  = (const float*)d_in[9];
    const float* lin1_b  = (const float*)d_in[10];
    const float* lin2_w  = (const float*)d_in[11];
    const float* lin2_b  = (const float*)d_in[12];

    const int* src = eidx;
    const int* dst = eidx + N_EDGES;

    // workspace carve (256B aligned)
    const size_t NB = (size_t)N_NODES * DIM * sizeof(float);   // 51.2 MB
    char* base = (char*)d_ws;
    size_t off = 0;
    auto carve = [&](size_t bytes) {
        char* p = base + off;
        off = (off + bytes + 255) & ~(size_t)255;
        return p;
    };
    float* bufA   = (float*)carve(NB);
    float* bufB   = (float*)carve(NB);
    int*   cnt    = (int*)  carve(N_NODES * sizeof(int));      // cnt -> dinv
    int*   rp     = (int*)  carve((N_NODES + 1) * sizeof(int));
    int*   cursor = (int*)  carve(N_NODES * sizeof(int));
    int*   csr    = (int*)  carve((size_t)N_EDGES * sizeof(int));
    int*   bsum   = (int*)  carve(SCAN_NBLK * sizeof(int));
    float* g      = (float*)carve((size_t)N_GRAPHS * DIM * sizeof(float));
    float* dinv   = (float*)cnt;   // in-place conversion after CSR build

    hipMemsetAsync(cnt, 0, N_NODES * sizeof(int), stream);
    hipMemsetAsync(g, 0, (size_t)N_GRAPHS * DIM * sizeof(float), stream);

    const int egrid4 = (N_EDGES / 4 + 255) / 256;
    const int ngrid  = (N_NODES + 7) / 8;
    const int ggrid  = (N_NODES + BM - 1) / BM;

    // ---- CSR build ----
    cnt_kernel<<<egrid4, 256, 0, stream>>>(dst, cnt, N_EDGES);
    scan1<<<SCAN_NBLK, SCAN_T, 0, stream>>>(cnt, rp, bsum, N_NODES);
    scan2<<<1, 128, 0, stream>>>(bsum, SCAN_NBLK);
    scan3<<<(N_NODES + 256) / 256, 256, 0, stream>>>(rp, cursor, bsum, N_NODES, N_EDGES);
    // 8 ranges x 128 slice-blocks = 1024 blocks; range = blockIdx & 7
    csr_fill<<<FILL_RANGES * 128, 256, 0, stream>>>(src, dst, cursor, csr, N_EDGES);
    make_dinv<<<(N_NODES + 255) / 256, 256, 0, stream>>>(cnt, N_NODES);

    // ---- GIN: bufA = x + segment_sum(x[src], dst) ----
    csr_gather<<<ngrid, 256, 0, stream>>>(rp, csr, x, bufA, N_NODES);

    // ---- GIN MLP ----
    gemm128<true,  false><<<ggrid, 256, 0, stream>>>(bufA, gin_w1, gin_b1, nullptr, bufB, N_NODES);
    gemm128<true,  false><<<ggrid, 256, 0, stream>>>(bufB, gin_w2, gin_b2, nullptr, bufA, N_NODES);

    // ---- GCN: u = dinv * (h @ gcn_w) -> bufB ----
    gemm128<false, true><<<ggrid, 256, 0, stream>>>(bufA, gcn_w, nullptr, dinv, bufB, N_NODES);

    // ---- GCN message pass: bufA[i] = u[i] + sum u[csr] ----
    csr_gather<<<ngrid, 256, 0, stream>>>(rp, csr, bufB, bufA, N_NODES);

    // ---- finalize + pool ----
    finalize_pool<<<(N_NODES + POOL_ROWS - 1) / POOL_ROWS, 128, 0, stream>>>(
        bufA, dinv, gcn_b, batch, g, N_NODES);

    // ---- head ----
    head_kernel<<<N_GRAPHS, 128, 0, stream>>>(
        g, lin1_w, lin1_b, lin2_w, lin2_b, (float*)d_out);
}

// Round 5
// 668.598 us; speedup vs baseline: 1.1025x; 1.0254x over previous
//
#include <hip/hip_runtime.h>
#include <hip/hip_bf16.h>

// Problem constants (match reference)
#define N_NODES  100000
#define N_EDGES  1600000
#define N_GRAPHS 2048
#define DIM      128   // IN_DIM == HIDDEN == 128

// ===========================================================================
// CSR construction: count -> 3-phase exclusive scan -> XCD-partitioned fill
// ===========================================================================
__global__ __launch_bounds__(256)
void cnt_kernel(const int* __restrict__ dst, int* __restrict__ cnt, int E)
{
    int e0 = (blockIdx.x * blockDim.x + threadIdx.x) * 4;
    if (e0 + 3 < E) {
        int4 d = *(const int4*)&dst[e0];
        atomicAdd(&cnt[d.x], 1);
        atomicAdd(&cnt[d.y], 1);
        atomicAdd(&cnt[d.z], 1);
        atomicAdd(&cnt[d.w], 1);
    } else {
        for (int e = e0; e < E; ++e) atomicAdd(&cnt[dst[e]], 1);
    }
}

#define SCAN_T     256
#define SCAN_E     4
#define SCAN_CHUNK 1024   // SCAN_T * SCAN_E
#define SCAN_NBLK  ((N_NODES + SCAN_CHUNK - 1) / SCAN_CHUNK)   // 98

__global__ __launch_bounds__(SCAN_T)
void scan1(const int* __restrict__ cnt, int* __restrict__ rp,
           int* __restrict__ bsum, int N)
{
    __shared__ int sh[SCAN_T];
    int b = blockIdx.x, t = threadIdx.x;
    int base = b * SCAN_CHUNK + t * SCAN_E;
    int v[SCAN_E];
    int s = 0;
#pragma unroll
    for (int i = 0; i < SCAN_E; ++i) {
        int idx = base + i;
        v[i] = (idx < N) ? cnt[idx] : 0;
        s += v[i];
    }
    sh[t] = s;
    __syncthreads();
    for (int off = 1; off < SCAN_T; off <<= 1) {
        int add = (t >= off) ? sh[t - off] : 0;
        __syncthreads();
        sh[t] += add;
        __syncthreads();
    }
    int excl = sh[t] - s;
    if (t == SCAN_T - 1) bsum[b] = sh[t];
    int run = excl;
#pragma unroll
    for (int i = 0; i < SCAN_E; ++i) {
        int idx = base + i;
        if (idx < N) rp[idx] = run;
        run += v[i];
    }
}

__global__ __launch_bounds__(128)
void scan2(int* __restrict__ bsum, int nb)
{
    __shared__ int sh[128];
    int t = threadIdx.x;
    int v = (t < nb) ? bsum[t] : 0;
    sh[t] = v;
    __syncthreads();
    for (int off = 1; off < 128; off <<= 1) {
        int add = (t >= off) ? sh[t - off] : 0;
        __syncthreads();
        sh[t] += add;
        __syncthreads();
    }
    if (t < nb) bsum[t] = sh[t] - v;   // exclusive
}

__global__ __launch_bounds__(256)
void scan3(int* __restrict__ rp, int* __restrict__ cursor,
           const int* __restrict__ bsum, int N, int E)
{
    int i = blockIdx.x * blockDim.x + threadIdx.x;
    if (i < N) {
        int v = rp[i] + bsum[i / SCAN_CHUNK];
        rp[i] = v;
        cursor[i] = v;
    }
    if (i == N) rp[N] = E;
}

// XCD-partitioned fill (round-4 win: keeps csr-line fills within one XCD L2)
#define FILL_RANGES 8
#define FILL_RSIZE  (N_NODES / FILL_RANGES)   // 12500 exact
__global__ __launch_bounds__(256)
void csr_fill(const int* __restrict__ src, const int* __restrict__ dst,
              int* __restrict__ cursor, int* __restrict__ csr, int E)
{
    const int r = blockIdx.x & (FILL_RANGES - 1);
    const int s = blockIdx.x >> 3;
    const int nslice = gridDim.x >> 3;
    const unsigned lo = (unsigned)(r * FILL_RSIZE);
    const int stride = nslice * 256 * 4;

    for (int e0 = (s * 256 + threadIdx.x) * 4; e0 < E; e0 += stride) {
        int4 d  = *(const int4*)&dst[e0];
        int4 sv = *(const int4*)&src[e0];
        if ((unsigned)(d.x - lo) < (unsigned)FILL_RSIZE) {
            int p = atomicAdd(&cursor[d.x], 1); csr[p] = sv.x;
        }
        if ((unsigned)(d.y - lo) < (unsigned)FILL_RSIZE) {
            int p = atomicAdd(&cursor[d.y], 1); csr[p] = sv.y;
        }
        if ((unsigned)(d.z - lo) < (unsigned)FILL_RSIZE) {
            int p = atomicAdd(&cursor[d.z], 1); csr[p] = sv.z;
        }
        if ((unsigned)(d.w - lo) < (unsigned)FILL_RSIZE) {
            int p = atomicAdd(&cursor[d.w], 1); csr[p] = sv.w;
        }
    }
}

// In-place reinterpret: int count -> float rsqrt(count + 1)
__global__ __launch_bounds__(256)
void make_dinv(int* __restrict__ cnt, int N)
{
    int i = blockIdx.x * blockDim.x + threadIdx.x;
    if (i < N) {
        float d = (float)cnt[i] + 1.0f;
        ((float*)cnt)[i] = rsqrtf(d);
    }
}

// ===========================================================================
// MEGA kernel: per block of 64 nodes —
//   phase 1: H[r] = x[node] + sum x[csr[e]]           (GIN aggregate, LDS)
//   phase 2: 3 in-LDS layer GEMMs (128x128 weights staged in BK=32 chunks):
//     L0: H = relu(H @ w1 + b1)
//     L1: H = relu(H @ w2 + b2)
//     L2: u  = dinv[row] * (H @ w3)   -> global
// H stride 129: a-load bank = (516*ty + ...)%32 -> 16 banks x 2-way = free.
// 256 threads; thread tile 4x8 (ty=tid>>4 row group, tx=tid&15 col group).
// LDS = 64*129*4 + 32*128*4 = 49.4 KB -> 3 blocks/CU.
// ===========================================================================
#define MB    64
#define HPAD  129

__global__ __launch_bounds__(256)
void mega(const int* __restrict__ rp, const int* __restrict__ csr,
          const float* __restrict__ x,
          const float* __restrict__ w1, const float* __restrict__ b1,
          const float* __restrict__ w2, const float* __restrict__ b2,
          const float* __restrict__ w3, const float* __restrict__ dinv,
          float* __restrict__ u_out, int N)
{
    __shared__ float H[MB][HPAD];
    __shared__ float Ws[32][DIM];

    const int tid  = threadIdx.x;
    const int row0 = blockIdx.x * MB;

    // ---- phase 1: gather (agg + x) ----
    {
        const int grp  = tid >> 5;     // 8 groups of 32 lanes
        const int lane = tid & 31;
        const float4* V4 = (const float4*)x;
        for (int r8 = 0; r8 < 8; ++r8) {
            int r = grp * 8 + r8;
            int node = row0 + r;
            float4 acc = make_float4(0.f, 0.f, 0.f, 0.f);
            if (node < N) {
                acc = V4[(size_t)node * 32 + lane];   // self term
                int e = rp[node], end = rp[node + 1];
                for (; e + 4 <= end; e += 4) {
                    int s0 = csr[e + 0], s1 = csr[e + 1];
                    int s2 = csr[e + 2], s3 = csr[e + 3];
                    float4 v0 = V4[(size_t)s0 * 32 + lane];
                    float4 v1 = V4[(size_t)s1 * 32 + lane];
                    float4 v2 = V4[(size_t)s2 * 32 + lane];
                    float4 v3 = V4[(size_t)s3 * 32 + lane];
                    acc.x += v0.x + v1.x + v2.x + v3.x;
                    acc.y += v0.y + v1.y + v2.y + v3.y;
                    acc.z += v0.z + v1.z + v2.z + v3.z;
                    acc.w += v0.w + v1.w + v2.w + v3.w;
                }
                for (; e < end; ++e) {
                    int s = csr[e];
                    float4 v = V4[(size_t)s * 32 + lane];
                    acc.x += v.x; acc.y += v.y; acc.z += v.z; acc.w += v.w;
                }
            }
            // stride-129 row: scalar stores (not 16B-aligned for odd rows)
            H[r][lane * 4 + 0] = acc.x;
            H[r][lane * 4 + 1] = acc.y;
            H[r][lane * 4 + 2] = acc.z;
            H[r][lane * 4 + 3] = acc.w;
        }
    }
    __syncthreads();

    // ---- phase 2: three layers ----
    const int tx = tid & 15;   // 16 col groups * 8 = 128
    const int ty = tid >> 4;   // 16 row groups * 4 = 64

    for (int layer = 0; layer < 3; ++layer) {
        const float* W = (layer == 0) ? w1 : (layer == 1) ? w2 : w3;
        float acc[4][8];
#pragma unroll
        for (int i = 0; i < 4; ++i)
#pragma unroll
            for (int j = 0; j < 8; ++j) acc[i][j] = 0.f;

        for (int kt = 0; kt < DIM; kt += 32) {
            // stage W[kt..kt+31][0..127] -> Ws
#pragma unroll
            for (int l = 0; l < 4; ++l) {
                int f  = tid + l * 256;
                int rr = f >> 5;
                int c4 = (f & 31) << 2;
                *(float4*)&Ws[rr][c4] = *(const float4*)&W[(size_t)(kt + rr) * DIM + c4];
            }
            __syncthreads();
#pragma unroll
            for (int kk = 0; kk < 32; ++kk) {
                float b[8];
                *(float4*)&b[0] = *(const float4*)&Ws[kk][tx * 8 + 0];
                *(float4*)&b[4] = *(const float4*)&Ws[kk][tx * 8 + 4];
                float a[4];
#pragma unroll
                for (int i = 0; i < 4; ++i) a[i] = H[ty * 4 + i][kt + kk];
#pragma unroll
                for (int i = 0; i < 4; ++i)
#pragma unroll
                    for (int j = 0; j < 8; ++j)
                        acc[i][j] = fmaf(a[i], b[j], acc[i][j]);
            }
            __syncthreads();
        }

        if (layer < 2) {
            const float* bias = (layer == 0) ? b1 : b2;
            float bv[8];
#pragma unroll
            for (int j = 0; j < 8; ++j) bv[j] = bias[tx * 8 + j];
#pragma unroll
            for (int i = 0; i < 4; ++i) {
#pragma unroll
                for (int j = 0; j < 8; ++j)
                    H[ty * 4 + i][tx * 8 + j] = fmaxf(acc[i][j] + bv[j], 0.f);
            }
            __syncthreads();
        } else {
            // u = dinv * (H @ w3), store global (coalesced float4 x2)
#pragma unroll
            for (int i = 0; i < 4; ++i) {
                int r = row0 + ty * 4 + i;
                if (r < N) {
                    float di = dinv[r];
                    float v[8];
#pragma unroll
                    for (int j = 0; j < 8; ++j) v[j] = di * acc[i][j];
                    *(float4*)&u_out[(size_t)r * DIM + tx * 8 + 0] = *(const float4*)&v[0];
                    *(float4*)&u_out[(size_t)r * DIM + tx * 8 + 4] = *(const float4*)&v[4];
                }
            }
        }
    }
}

// ===========================================================================
// Fused GCN gather + finalize + global_add_pool:
//   h_i = relu(dinv_i * (u_i + sum u[csr]) + b);  g[batch[i]] += h_i
// 8 groups x 8 nodes per block; batch sorted -> run-length local float4 sums,
// flush 4 atomics/lane per run boundary.
// ===========================================================================
#define P2_NODES 64
__global__ __launch_bounds__(256)
void gcn_gather_pool(const int* __restrict__ rp, const int* __restrict__ csr,
                     const float* __restrict__ u, const float* __restrict__ dinv,
                     const float* __restrict__ bias, const int* __restrict__ batch,
                     float* __restrict__ g, int N)
{
    const int grp  = threadIdx.x >> 5;
    const int lane = threadIdx.x & 31;
    const int n0   = blockIdx.x * P2_NODES + grp * 8;
    const float4* V4 = (const float4*)u;

    float4 bj;
    bj.x = bias[lane * 4 + 0];
    bj.y = bias[lane * 4 + 1];
    bj.z = bias[lane * 4 + 2];
    bj.w = bias[lane * 4 + 3];

    float4 lsum = make_float4(0.f, 0.f, 0.f, 0.f);
    int prev = -1;

    for (int k = 0; k < 8; ++k) {
        int node = n0 + k;
        if (node >= N) break;
        float4 acc = V4[(size_t)node * 32 + lane];   // self term u_i
        int e = rp[node], end = rp[node + 1];
        for (; e + 4 <= end; e += 4) {
            int s0 = csr[e + 0], s1 = csr[e + 1];
            int s2 = csr[e + 2], s3 = csr[e + 3];
            float4 v0 = V4[(size_t)s0 * 32 + lane];
            float4 v1 = V4[(size_t)s1 * 32 + lane];
            float4 v2 = V4[(size_t)s2 * 32 + lane];
            float4 v3 = V4[(size_t)s3 * 32 + lane];
            acc.x += v0.x + v1.x + v2.x + v3.x;
            acc.y += v0.y + v1.y + v2.y + v3.y;
            acc.z += v0.z + v1.z + v2.z + v3.z;
            acc.w += v0.w + v1.w + v2.w + v3.w;
        }
        for (; e < end; ++e) {
            int s = csr[e];
            float4 v = V4[(size_t)s * 32 + lane];
            acc.x += v.x; acc.y += v.y; acc.z += v.z; acc.w += v.w;
        }
        float di = dinv[node];
        float4 h;
        h.x = fmaxf(fmaf(di, acc.x, bj.x), 0.f);
        h.y = fmaxf(fmaf(di, acc.y, bj.y), 0.f);
        h.z = fmaxf(fmaf(di, acc.z, bj.z), 0.f);
        h.w = fmaxf(fmaf(di, acc.w, bj.w), 0.f);

        int b = batch[node];
        if (b != prev) {
            if (prev >= 0) {
                float* gp = &g[(size_t)prev * DIM + lane * 4];
                atomicAdd(gp + 0, lsum.x);
                atomicAdd(gp + 1, lsum.y);
                atomicAdd(gp + 2, lsum.z);
                atomicAdd(gp + 3, lsum.w);
            }
            lsum = make_float4(0.f, 0.f, 0.f, 0.f);
            prev = b;
        }
        lsum.x += h.x; lsum.y += h.y; lsum.z += h.z; lsum.w += h.w;
    }
    if (prev >= 0) {
        float* gp = &g[(size_t)prev * DIM + lane * 4];
        atomicAdd(gp + 0, lsum.x);
        atomicAdd(gp + 1, lsum.y);
        atomicAdd(gp + 2, lsum.z);
        atomicAdd(gp + 3, lsum.w);
    }
}

// ===========================================================================
// Head: out[gid] = relu(g[gid] @ lin1_w + b1) @ lin2_w + b2
// ===========================================================================
__global__ __launch_bounds__(128)
void head_kernel(const float* __restrict__ g, const float* __restrict__ w1,
                 const float* __restrict__ b1, const float* __restrict__ w2,
                 const float* __restrict__ b2, float* __restrict__ out)
{
    __shared__ float gs[DIM];
    __shared__ float red[6];
    int gid = blockIdx.x;
    int t = threadIdx.x;

    gs[t] = g[(size_t)gid * DIM + t];
    __syncthreads();

    float acc = b1[t];
#pragma unroll
    for (int k = 0; k < DIM; ++k) acc = fmaf(gs[k], w1[k * DIM + t], acc);
    float h = fmaxf(acc, 0.f);

    float c0 = h * w2[t * 3 + 0];
    float c1 = h * w2[t * 3 + 1];
    float c2 = h * w2[t * 3 + 2];
#pragma unroll
    for (int off = 32; off >= 1; off >>= 1) {
        c0 += __shfl_down(c0, off);
        c1 += __shfl_down(c1, off);
        c2 += __shfl_down(c2, off);
    }
    int wave = t >> 6;
    if ((t & 63) == 0) {
        red[wave * 3 + 0] = c0;
        red[wave * 3 + 1] = c1;
        red[wave * 3 + 2] = c2;
    }
    __syncthreads();
    if (t == 0) {
        out[(size_t)gid * 3 + 0] = red[0] + red[3] + b2[0];
        out[(size_t)gid * 3 + 1] = red[1] + red[4] + b2[1];
        out[(size_t)gid * 3 + 2] = red[2] + red[5] + b2[2];
    }
}

// ===========================================================================
extern "C" void kernel_launch(void* const* d_in, const int* in_sizes, int n_in,
                              void* d_out, int out_size, void* d_ws, size_t ws_size,
                              hipStream_t stream)
{
    const float* x       = (const float*)d_in[0];
    const int*   eidx    = (const int*)d_in[1];
    const int*   batch   = (const int*)d_in[2];
    const float* gin_w1  = (const float*)d_in[3];
    const float* gin_b1  = (const float*)d_in[4];
    const float* gin_w2  = (const float*)d_in[5];
    const float* gin_b2  = (const float*)d_in[6];
    const float* gcn_w   = (const float*)d_in[7];
    const float* gcn_b   = (const float*)d_in[8];
    const float* lin1_w  = (const float*)d_in[9];
    const float* lin1_b  = (const float*)d_in[10];
    const float* lin2_w  = (const float*)d_in[11];
    const float* lin2_b  = (const float*)d_in[12];

    const int* src = eidx;
    const int* dst = eidx + N_EDGES;

    // workspace carve (256B aligned)
    const size_t NB = (size_t)N_NODES * DIM * sizeof(float);   // 51.2 MB
    char* base = (char*)d_ws;
    size_t off = 0;
    auto carve = [&](size_t bytes) {
        char* p = base + off;
        off = (off + bytes + 255) & ~(size_t)255;
        return p;
    };
    float* u      = (float*)carve(NB);                         // GCN u rows
    int*   cnt    = (int*)  carve(N_NODES * sizeof(int));      // cnt -> dinv
    int*   rp     = (int*)  carve((N_NODES + 1) * sizeof(int));
    int*   cursor = (int*)  carve(N_NODES * sizeof(int));
    int*   csr    = (int*)  carve((size_t)N_EDGES * sizeof(int));
    int*   bsum   = (int*)  carve(SCAN_NBLK * sizeof(int));
    float* g      = (float*)carve((size_t)N_GRAPHS * DIM * sizeof(float));
    float* dinv   = (float*)cnt;   // in-place conversion after CSR build

    hipMemsetAsync(cnt, 0, N_NODES * sizeof(int), stream);
    hipMemsetAsync(g, 0, (size_t)N_GRAPHS * DIM * sizeof(float), stream);

    const int egrid4 = (N_EDGES / 4 + 255) / 256;
    const int mgrid  = (N_NODES + MB - 1) / MB;          // 1563
    const int pgrid  = (N_NODES + P2_NODES - 1) / P2_NODES;

    // ---- CSR build ----
    cnt_kernel<<<egrid4, 256, 0, stream>>>(dst, cnt, N_EDGES);
    scan1<<<SCAN_NBLK, SCAN_T, 0, stream>>>(cnt, rp, bsum, N_NODES);
    scan2<<<1, 128, 0, stream>>>(bsum, SCAN_NBLK);
    scan3<<<(N_NODES + 256) / 256, 256, 0, stream>>>(rp, cursor, bsum, N_NODES, N_EDGES);
    csr_fill<<<FILL_RANGES * 128, 256, 0, stream>>>(src, dst, cursor, csr, N_EDGES);
    make_dinv<<<(N_NODES + 255) / 256, 256, 0, stream>>>(cnt, N_NODES);

    // ---- fused GIN gather + MLP + GCN GEMM -> u ----
    mega<<<mgrid, 256, 0, stream>>>(rp, csr, x, gin_w1, gin_b1,
                                    gin_w2, gin_b2, gcn_w, dinv, u, N_NODES);

    // ---- fused GCN gather + finalize + pool -> g ----
    gcn_gather_pool<<<pgrid, 256, 0, stream>>>(rp, csr, u, dinv, gcn_b,
                                               batch, g, N_NODES);

    // ---- head ----
    head_kernel<<<N_GRAPHS, 128, 0, stream>>>(
        g, lin1_w, lin1_b, lin2_w, lin2_b, (float*)d_out);
}